// Round 8
// baseline (141.065 us; speedup 1.0000x reference)
//
#include <hip/hip_runtime.h>

// ---------------- problem constants ----------------
#define NS 32768
// output flat offsets (fp32 elements)
#define OUT1_BASE (NS * 256)                 // 8388608
#define OUT2_BASE (OUT1_BASE + NS * 576)     // 27262976
#define OUT3_BASE (OUT2_BASE + NS * 640)     // 48234496

#define NITEMS (NS * 32)        // 1048576 (sample, channel-pair) items
#define NTHREADS (1024 * 256)   // persistent grid: 1024 blocks x 256
#define ITERS (NITEMS / NTHREADS)  // 4

typedef float f2 __attribute__((ext_vector_type(2)));

// ================= compile-time U construction =================
namespace cgc {

constexpr double hfact(int n) { double r = 1.0; for (int i = 2; i <= n; ++i) r *= (double)i; return r; }

constexpr double csqrt(double a) {
    if (a <= 0.0) return 0.0;
    double x = a > 1.0 ? a : 1.0;
    for (int i = 0; i < 64; ++i) x = 0.5 * (x + a / x);
    return x;
}

constexpr double cg_coeff(int j1, int m1, int j2, int m2, int J, int M) {
    if (m1 + m2 != M) return 0.0;
    double pref = (2.0 * J + 1.0) * hfact(j1 + j2 - J) * hfact(j1 - j2 + J)
                * hfact(-j1 + j2 + J) / hfact(j1 + j2 + J + 1);
    pref *= hfact(J + M) * hfact(J - M) * hfact(j1 - m1) * hfact(j1 + m1)
          * hfact(j2 - m2) * hfact(j2 + m2);
    int kmin = 0;
    if (j2 - J - m1 > kmin) kmin = j2 - J - m1;
    if (j1 + m2 - J > kmin) kmin = j1 + m2 - J;
    int kmax = j1 + j2 - J;
    if (j1 - m1 < kmax) kmax = j1 - m1;
    if (j2 + m2 < kmax) kmax = j2 + m2;
    double s = 0.0;
    for (int k = kmin; k <= kmax; ++k) {
        double d = hfact(k) * hfact(j1 + j2 - J - k) * hfact(j1 - m1 - k)
                 * hfact(j2 + m2 - k) * hfact(J - j2 + m1 + k) * hfact(J - j1 - m2 + k);
        s += ((k & 1) ? -1.0 : 1.0) / d;
    }
    return csqrt(pref) * s;
}

struct C2 { double re; double im; };
constexpr C2 cmul(C2 a, C2 b) { return { a.re * b.re - a.im * b.im, a.re * b.im + a.im * b.re }; }
constexpr C2 cadd(C2 a, C2 b) { return { a.re + b.re, a.im + b.im }; }
constexpr C2 cscale(C2 a, double s) { return { a.re * s, a.im * s }; }
constexpr C2 conjc(C2 a) { return { a.re, -a.im }; }

struct R2C { C2 r[81]; };

constexpr R2C real2complex(int L) {
    R2C R{};
    int D = 2 * L + 1;
    double isq2 = 1.0 / csqrt(2.0);
    for (int m = -L; m <= L; ++m) {
        double sgn = (m & 1) ? -1.0 : 1.0;
        if (m < 0) {
            R.r[(L - m) * D + (L + m)] = { 0.0, isq2 * sgn };
            R.r[(L + m) * D + (L + m)] = { 0.0, -isq2 };
        } else if (m == 0) {
            R.r[L * D + L] = { 1.0, 0.0 };
        } else {
            R.r[(L - m) * D + (L + m)] = { isq2, 0.0 };
            R.r[(L + m) * D + (L + m)] = { isq2 * sgn, 0.0 };
        }
    }
    return R;
}

struct Blk { double v[225]; };

constexpr Blk cg_real(int l1, int l2, int L) {
    Blk out{};
    int D1 = 2 * l1 + 1, D2 = 2 * l2 + 1, DL = 2 * L + 1;
    double ccg[225] = {};
    for (int m1 = -l1; m1 <= l1; ++m1)
        for (int m2 = -l2; m2 <= l2; ++m2) {
            int M = m1 + m2;
            if (M >= -L && M <= L)
                ccg[((m1 + l1) * D2 + (m2 + l2)) * DL + (M + L)] = cg_coeff(l1, m1, l2, m2, L, M);
        }
    R2C R1 = real2complex(l1);
    R2C R2 = real2complex(l2);
    R2C RL = real2complex(L);
    bool even = ((l1 + l2 + L) % 2) == 0;
    for (int a = 0; a < D1; ++a)
        for (int b = 0; b < D2; ++b) {
            C2 tmp[9] = {};
            for (int M = 0; M < DL; ++M) {
                C2 s = { 0.0, 0.0 };
                for (int m = 0; m < D1; ++m)
                    for (int nn = 0; nn < D2; ++nn) {
                        double cc = ccg[(m * D2 + nn) * DL + M];
                        if (cc != 0.0)
                            s = cadd(s, cscale(cmul(R1.r[m * D1 + a], R2.r[nn * D2 + b]), cc));
                    }
                tmp[M] = s;
            }
            for (int k = 0; k < DL; ++k) {
                C2 s = { 0.0, 0.0 };
                for (int M = 0; M < DL; ++M)
                    s = cadd(s, cmul(tmp[M], conjc(RL.r[M * DL + k])));
                out.v[(a * D2 + b) * DL + k] = even ? s.re : s.im;
            }
        }
    return out;
}

constexpr Blk B2_0 = cg_real(1, 1, 0);
constexpr Blk B2_1 = cg_real(1, 1, 1);
constexpr Blk B2_2 = cg_real(1, 1, 2);
constexpr Blk B4_0 = cg_real(2, 2, 0);
constexpr Blk B4_1 = cg_real(2, 2, 1);
constexpr Blk B4_2 = cg_real(2, 2, 2);
constexpr Blk B4_3 = cg_real(2, 2, 3);
constexpr Blk B4_4 = cg_real(2, 2, 4);

struct U9T  { float u[81];  };
struct U25T { float u[625]; };

constexpr U9T build_U9() {
    U9T U{};
    const Blk* bl[3] = { &B2_0, &B2_1, &B2_2 };
    int off = 0;
    for (int L = 0; L <= 2; ++L) {
        int DL = 2 * L + 1;
        for (int a = 0; a < 3; ++a)
            for (int b = 0; b < 3; ++b)
                for (int k = 0; k < DL; ++k)
                    U.u[(a * 3 + b) * 9 + (off + k)] = (float)bl[L]->v[(a * 3 + b) * DL + k];
        off += DL;
    }
    return U;
}

constexpr U25T build_U25() {
    U25T U{};
    const Blk* bl[5] = { &B4_0, &B4_1, &B4_2, &B4_3, &B4_4 };
    int off = 0;
    for (int L = 0; L <= 4; ++L) {
        int DL = 2 * L + 1;
        for (int a = 0; a < 5; ++a)
            for (int b = 0; b < 5; ++b)
                for (int k = 0; k < DL; ++k)
                    U.u[(a * 5 + b) * 25 + (off + k)] = (float)bl[L]->v[(a * 5 + b) * DL + k];
        off += DL;
    }
    return U;
}

constexpr U9T  U9c  = build_U9();
constexpr U25T U25c = build_U25();

} // namespace cgc

// ================= persistent grid-stride f2 kernel =================
// 1024 blocks x 256 threads, ALL co-resident (4 blocks/CU at VGPR<=128):
// zero dispatch-tail raggedness. Each thread processes ITERS=4 items
// (sample, channel-pair), per-item batched prefetch (R6 structure).

__global__ __launch_bounds__(256) void tp_gs_kernel(
    const float* __restrict__ f1_0, const float* __restrict__ f1_1,
    const float* __restrict__ f1_2, const float* __restrict__ f1_3,
    const float* __restrict__ f2_0, const float* __restrict__ f2_1,
    const float* __restrict__ f2_2, const float* __restrict__ f2_3,
    float* __restrict__ out)
{
    using namespace cgc;
    const int tid = blockIdx.x * 256 + threadIdx.x;

#define LD2(p, i) (*(const f2*)((p) + (i)))
#define ST2(v, p, i) __builtin_nontemporal_store((v), (f2*)((p) + (i)))

#pragma unroll 1
    for (int it = 0; it < ITERS; ++it) {
        const int item = tid + it * NTHREADS;
        const int n = item >> 5;          // sample
        const int cc = (item & 31) * 2;   // channel (even)
        const int r0 = n * 256, r1 = n * 576, r2 = n * 640, r3 = n * 448;

        // ================ LOAD PHASE: all 30 f2 loads ================
        f2 z1 = LD2(f1_0, r0 + 192 + cc);
        f2 z2 = LD2(f2_0, r0 + 192 + cc);
        f2 a1[4], a2[4];
        a1[0] = LD2(f1_0, r0 + 128 + cc);
        a2[0] = LD2(f2_0, r0 + 128 + cc);
#pragma unroll
        for (int m = 0; m < 3; ++m) {
            a1[1 + m] = LD2(f1_1, r1 + m * 192 + 128 + cc);
            a2[1 + m] = LD2(f2_1, r1 + m * 192 + 128 + cc);
        }
        f2 b1[9], b2[9];
        b1[0] = LD2(f1_0, r0 + 64 + cc);
        b2[0] = LD2(f2_0, r0 + 64 + cc);
#pragma unroll
        for (int m = 0; m < 3; ++m) {
            b1[1 + m] = LD2(f1_1, r1 + m * 192 + 64 + cc);
            b2[1 + m] = LD2(f2_1, r1 + m * 192 + 64 + cc);
        }
#pragma unroll
        for (int m = 0; m < 5; ++m) {
            b1[4 + m] = LD2(f1_2, r2 + m * 128 + 64 + cc);
            b2[4 + m] = LD2(f2_2, r2 + m * 128 + 64 + cc);
        }
        f2 c1[16], c2[16];
        c1[0] = LD2(f1_0, r0 + cc);
        c2[0] = LD2(f2_0, r0 + cc);
#pragma unroll
        for (int m = 0; m < 3; ++m) {
            c1[1 + m] = LD2(f1_1, r1 + m * 192 + cc);
            c2[1 + m] = LD2(f2_1, r1 + m * 192 + cc);
        }
#pragma unroll
        for (int m = 0; m < 5; ++m) {
            c1[4 + m] = LD2(f1_2, r2 + m * 128 + cc);
            c2[4 + m] = LD2(f2_2, r2 + m * 128 + cc);
        }
#pragma unroll
        for (int m = 0; m < 7; ++m) {
            c1[9 + m] = LD2(f1_3, r3 + m * 64 + cc);
            c2[9 + m] = LD2(f2_3, r3 + m * 64 + cc);
        }

        __builtin_amdgcn_sched_barrier(0);

        // ================ COMPUTE PHASE ================
        ST2(z1 * z2, out, r0 + cc);

        // band 1 (outputs L=0,1)
        {
            f2 A[9], B[9];
#pragma unroll
            for (int M = 0; M < 9; ++M) {
                f2 sa = { 0.f, 0.f }, sb = { 0.f, 0.f };
#pragma unroll
                for (int N = 0; N < 4; ++N)
                    if (U9c.u[M * 9 + N] != 0.0f) {
                        sa += U9c.u[M * 9 + N] * a1[N];
                        sb += U9c.u[M * 9 + N] * a2[N];
                    }
                A[M] = sa; B[M] = sb;
            }
            f2 C[9];
#pragma unroll
            for (int i = 0; i < 3; ++i)
#pragma unroll
                for (int k = 0; k < 3; ++k) {
                    f2 sC = { 0.f, 0.f };
#pragma unroll
                    for (int j = 0; j < 3; ++j) sC += A[i * 3 + j] * B[j * 3 + k];
                    C[i * 3 + k] = sC;
                }
            f2 y[4];
#pragma unroll
            for (int M = 0; M < 4; ++M) {
                f2 sY = { 0.f, 0.f };
#pragma unroll
                for (int N = 0; N < 9; ++N)
                    if (U9c.u[N * 9 + M] != 0.0f) sY += U9c.u[N * 9 + M] * C[N];
                y[M] = sY;
            }
            ST2(y[0], out, r0 + 64 + cc);
#pragma unroll
            for (int m = 0; m < 3; ++m)
                ST2(y[1 + m], out, OUT1_BASE + r1 + m * 192 + cc);
        }

        // band 2 (outputs L=0..2)
        {
            f2 A[9], B[9];
#pragma unroll
            for (int M = 0; M < 9; ++M) {
                f2 sa = { 0.f, 0.f }, sb = { 0.f, 0.f };
#pragma unroll
                for (int N = 0; N < 9; ++N)
                    if (U9c.u[M * 9 + N] != 0.0f) {
                        sa += U9c.u[M * 9 + N] * b1[N];
                        sb += U9c.u[M * 9 + N] * b2[N];
                    }
                A[M] = sa; B[M] = sb;
            }
            f2 C[9];
#pragma unroll
            for (int i = 0; i < 3; ++i)
#pragma unroll
                for (int k = 0; k < 3; ++k) {
                    f2 sC = { 0.f, 0.f };
#pragma unroll
                    for (int j = 0; j < 3; ++j) sC += A[i * 3 + j] * B[j * 3 + k];
                    C[i * 3 + k] = sC;
                }
            f2 y[9];
#pragma unroll
            for (int M = 0; M < 9; ++M) {
                f2 sY = { 0.f, 0.f };
#pragma unroll
                for (int N = 0; N < 9; ++N)
                    if (U9c.u[N * 9 + M] != 0.0f) sY += U9c.u[N * 9 + M] * C[N];
                y[M] = sY;
            }
            ST2(y[0], out, r0 + 128 + cc);
#pragma unroll
            for (int m = 0; m < 3; ++m)
                ST2(y[1 + m], out, OUT1_BASE + r1 + m * 192 + 64 + cc);
#pragma unroll
            for (int m = 0; m < 5; ++m)
                ST2(y[4 + m], out, OUT2_BASE + r2 + m * 128 + cc);
        }

        // band 3 (outputs L=0..3)
        {
            f2 A[25], B[25];
#pragma unroll
            for (int M = 0; M < 25; ++M) {
                f2 sa = { 0.f, 0.f }, sb = { 0.f, 0.f };
#pragma unroll
                for (int N = 0; N < 16; ++N)
                    if (U25c.u[M * 25 + N] != 0.0f) {
                        sa += U25c.u[M * 25 + N] * c1[N];
                        sb += U25c.u[M * 25 + N] * c2[N];
                    }
                A[M] = sa; B[M] = sb;
            }
            f2 C[25];
#pragma unroll
            for (int i = 0; i < 5; ++i)
#pragma unroll
                for (int k = 0; k < 5; ++k) {
                    f2 sC = { 0.f, 0.f };
#pragma unroll
                    for (int j = 0; j < 5; ++j) sC += A[i * 5 + j] * B[j * 5 + k];
                    C[i * 5 + k] = sC;
                }
            f2 y[16];
#pragma unroll
            for (int M = 0; M < 16; ++M) {
                f2 sY = { 0.f, 0.f };
#pragma unroll
                for (int N = 0; N < 25; ++N)
                    if (U25c.u[N * 25 + M] != 0.0f) sY += U25c.u[N * 25 + M] * C[N];
                y[M] = sY;
            }
            ST2(y[0], out, r0 + 192 + cc);
#pragma unroll
            for (int m = 0; m < 3; ++m)
                ST2(y[1 + m], out, OUT1_BASE + r1 + m * 192 + 128 + cc);
#pragma unroll
            for (int m = 0; m < 5; ++m)
                ST2(y[4 + m], out, OUT2_BASE + r2 + m * 128 + 64 + cc);
#pragma unroll
            for (int m = 0; m < 7; ++m)
                ST2(y[9 + m], out, OUT3_BASE + r3 + m * 64 + cc);
        }
    }
#undef LD2
#undef ST2
}

// ---------------- launch ----------------
extern "C" void kernel_launch(void* const* d_in, const int* in_sizes, int n_in,
                              void* d_out, int out_size, void* d_ws, size_t ws_size,
                              hipStream_t stream)
{
    const float* f1_0 = (const float*)d_in[0];
    const float* f1_1 = (const float*)d_in[1];
    const float* f1_2 = (const float*)d_in[2];
    const float* f1_3 = (const float*)d_in[3];
    const float* f2_0 = (const float*)d_in[4];
    const float* f2_1 = (const float*)d_in[5];
    const float* f2_2 = (const float*)d_in[6];
    const float* f2_3 = (const float*)d_in[7];
    float* out = (float*)d_out;

    dim3 blk(256);
    dim3 grid(1024);   // persistent: 4 blocks/CU, all co-resident, zero tail

    tp_gs_kernel<<<grid, blk, 0, stream>>>(f1_0, f1_1, f1_2, f1_3,
                                           f2_0, f2_1, f2_2, f2_3, out);
}

// Round 9
// 137.378 us; speedup vs baseline: 1.0268x; 1.0268x over previous
//
#include <hip/hip_runtime.h>

// ---------------- problem constants ----------------
#define NS 32768
// output flat offsets (fp32 elements)
#define OUT1_BASE (NS * 256)                 // 8388608
#define OUT2_BASE (OUT1_BASE + NS * 576)     // 27262976
#define OUT3_BASE (OUT2_BASE + NS * 640)     // 48234496

typedef float f2 __attribute__((ext_vector_type(2)));

// ================= compile-time U construction =================
namespace cgc {

constexpr double hfact(int n) { double r = 1.0; for (int i = 2; i <= n; ++i) r *= (double)i; return r; }

constexpr double csqrt(double a) {
    if (a <= 0.0) return 0.0;
    double x = a > 1.0 ? a : 1.0;
    for (int i = 0; i < 64; ++i) x = 0.5 * (x + a / x);
    return x;
}

constexpr double cg_coeff(int j1, int m1, int j2, int m2, int J, int M) {
    if (m1 + m2 != M) return 0.0;
    double pref = (2.0 * J + 1.0) * hfact(j1 + j2 - J) * hfact(j1 - j2 + J)
                * hfact(-j1 + j2 + J) / hfact(j1 + j2 + J + 1);
    pref *= hfact(J + M) * hfact(J - M) * hfact(j1 - m1) * hfact(j1 + m1)
          * hfact(j2 - m2) * hfact(j2 + m2);
    int kmin = 0;
    if (j2 - J - m1 > kmin) kmin = j2 - J - m1;
    if (j1 + m2 - J > kmin) kmin = j1 + m2 - J;
    int kmax = j1 + j2 - J;
    if (j1 - m1 < kmax) kmax = j1 - m1;
    if (j2 + m2 < kmax) kmax = j2 + m2;
    double s = 0.0;
    for (int k = kmin; k <= kmax; ++k) {
        double d = hfact(k) * hfact(j1 + j2 - J - k) * hfact(j1 - m1 - k)
                 * hfact(j2 + m2 - k) * hfact(J - j2 + m1 + k) * hfact(J - j1 - m2 + k);
        s += ((k & 1) ? -1.0 : 1.0) / d;
    }
    return csqrt(pref) * s;
}

struct C2 { double re; double im; };
constexpr C2 cmul(C2 a, C2 b) { return { a.re * b.re - a.im * b.im, a.re * b.im + a.im * b.re }; }
constexpr C2 cadd(C2 a, C2 b) { return { a.re + b.re, a.im + b.im }; }
constexpr C2 cscale(C2 a, double s) { return { a.re * s, a.im * s }; }
constexpr C2 conjc(C2 a) { return { a.re, -a.im }; }

struct R2C { C2 r[81]; };

constexpr R2C real2complex(int L) {
    R2C R{};
    int D = 2 * L + 1;
    double isq2 = 1.0 / csqrt(2.0);
    for (int m = -L; m <= L; ++m) {
        double sgn = (m & 1) ? -1.0 : 1.0;
        if (m < 0) {
            R.r[(L - m) * D + (L + m)] = { 0.0, isq2 * sgn };
            R.r[(L + m) * D + (L + m)] = { 0.0, -isq2 };
        } else if (m == 0) {
            R.r[L * D + L] = { 1.0, 0.0 };
        } else {
            R.r[(L - m) * D + (L + m)] = { isq2, 0.0 };
            R.r[(L + m) * D + (L + m)] = { isq2 * sgn, 0.0 };
        }
    }
    return R;
}

struct Blk { double v[225]; };

constexpr Blk cg_real(int l1, int l2, int L) {
    Blk out{};
    int D1 = 2 * l1 + 1, D2 = 2 * l2 + 1, DL = 2 * L + 1;
    double ccg[225] = {};
    for (int m1 = -l1; m1 <= l1; ++m1)
        for (int m2 = -l2; m2 <= l2; ++m2) {
            int M = m1 + m2;
            if (M >= -L && M <= L)
                ccg[((m1 + l1) * D2 + (m2 + l2)) * DL + (M + L)] = cg_coeff(l1, m1, l2, m2, L, M);
        }
    R2C R1 = real2complex(l1);
    R2C R2 = real2complex(l2);
    R2C RL = real2complex(L);
    bool even = ((l1 + l2 + L) % 2) == 0;
    for (int a = 0; a < D1; ++a)
        for (int b = 0; b < D2; ++b) {
            C2 tmp[9] = {};
            for (int M = 0; M < DL; ++M) {
                C2 s = { 0.0, 0.0 };
                for (int m = 0; m < D1; ++m)
                    for (int nn = 0; nn < D2; ++nn) {
                        double cc = ccg[(m * D2 + nn) * DL + M];
                        if (cc != 0.0)
                            s = cadd(s, cscale(cmul(R1.r[m * D1 + a], R2.r[nn * D2 + b]), cc));
                    }
                tmp[M] = s;
            }
            for (int k = 0; k < DL; ++k) {
                C2 s = { 0.0, 0.0 };
                for (int M = 0; M < DL; ++M)
                    s = cadd(s, cmul(tmp[M], conjc(RL.r[M * DL + k])));
                out.v[(a * D2 + b) * DL + k] = even ? s.re : s.im;
            }
        }
    return out;
}

constexpr Blk B2_0 = cg_real(1, 1, 0);
constexpr Blk B2_1 = cg_real(1, 1, 1);
constexpr Blk B2_2 = cg_real(1, 1, 2);
constexpr Blk B4_0 = cg_real(2, 2, 0);
constexpr Blk B4_1 = cg_real(2, 2, 1);
constexpr Blk B4_2 = cg_real(2, 2, 2);
constexpr Blk B4_3 = cg_real(2, 2, 3);
constexpr Blk B4_4 = cg_real(2, 2, 4);

struct U9T  { float u[81];  };
struct U25T { float u[625]; };

constexpr U9T build_U9() {
    U9T U{};
    const Blk* bl[3] = { &B2_0, &B2_1, &B2_2 };
    int off = 0;
    for (int L = 0; L <= 2; ++L) {
        int DL = 2 * L + 1;
        for (int a = 0; a < 3; ++a)
            for (int b = 0; b < 3; ++b)
                for (int k = 0; k < DL; ++k)
                    U.u[(a * 3 + b) * 9 + (off + k)] = (float)bl[L]->v[(a * 3 + b) * DL + k];
        off += DL;
    }
    return U;
}

constexpr U25T build_U25() {
    U25T U{};
    const Blk* bl[5] = { &B4_0, &B4_1, &B4_2, &B4_3, &B4_4 };
    int off = 0;
    for (int L = 0; L <= 4; ++L) {
        int DL = 2 * L + 1;
        for (int a = 0; a < 5; ++a)
            for (int b = 0; b < 5; ++b)
                for (int k = 0; k < DL; ++k)
                    U.u[(a * 5 + b) * 25 + (off + k)] = (float)bl[L]->v[(a * 5 + b) * DL + k];
        off += DL;
    }
    return U;
}

constexpr U9T  U9c  = build_U9();
constexpr U25T U25c = build_U25();

} // namespace cgc

// ================= float2 + pinned-prefetch fused kernel =================
// Best-measured variant (R6, 137.5 us). One thread = (sample, channel pair).
// All 30 f2 loads issued up front, sched_barrier(0) pins them before compute;
// NT stores keep the 252 MB output stream out of L3 so inputs stay resident
// across graph replays (FETCH stays ~252 MB instead of ~503 MB).

__global__ __launch_bounds__(256) void tp_f2p_kernel(
    const float* __restrict__ f1_0, const float* __restrict__ f1_1,
    const float* __restrict__ f1_2, const float* __restrict__ f1_3,
    const float* __restrict__ f2_0, const float* __restrict__ f2_1,
    const float* __restrict__ f2_2, const float* __restrict__ f2_3,
    float* __restrict__ out)
{
    using namespace cgc;
    const int t = blockIdx.x * 256 + threadIdx.x;
    const int n = t >> 5;          // sample
    const int cc = (t & 31) * 2;   // channel (even)
    const int r0 = n * 256, r1 = n * 576, r2 = n * 640, r3 = n * 448;

#define LD2(p, i) (*(const f2*)((p) + (i)))
#define ST2(v, p, i) __builtin_nontemporal_store((v), (f2*)((p) + (i)))

    // ================ LOAD PHASE: all 30 f2 loads ================
    f2 z1 = LD2(f1_0, r0 + 192 + cc);
    f2 z2 = LD2(f2_0, r0 + 192 + cc);
    f2 a1[4], a2[4];
    a1[0] = LD2(f1_0, r0 + 128 + cc);
    a2[0] = LD2(f2_0, r0 + 128 + cc);
#pragma unroll
    for (int m = 0; m < 3; ++m) {
        a1[1 + m] = LD2(f1_1, r1 + m * 192 + 128 + cc);
        a2[1 + m] = LD2(f2_1, r1 + m * 192 + 128 + cc);
    }
    f2 b1[9], b2[9];
    b1[0] = LD2(f1_0, r0 + 64 + cc);
    b2[0] = LD2(f2_0, r0 + 64 + cc);
#pragma unroll
    for (int m = 0; m < 3; ++m) {
        b1[1 + m] = LD2(f1_1, r1 + m * 192 + 64 + cc);
        b2[1 + m] = LD2(f2_1, r1 + m * 192 + 64 + cc);
    }
#pragma unroll
    for (int m = 0; m < 5; ++m) {
        b1[4 + m] = LD2(f1_2, r2 + m * 128 + 64 + cc);
        b2[4 + m] = LD2(f2_2, r2 + m * 128 + 64 + cc);
    }
    f2 c1[16], c2[16];
    c1[0] = LD2(f1_0, r0 + cc);
    c2[0] = LD2(f2_0, r0 + cc);
#pragma unroll
    for (int m = 0; m < 3; ++m) {
        c1[1 + m] = LD2(f1_1, r1 + m * 192 + cc);
        c2[1 + m] = LD2(f2_1, r1 + m * 192 + cc);
    }
#pragma unroll
    for (int m = 0; m < 5; ++m) {
        c1[4 + m] = LD2(f1_2, r2 + m * 128 + cc);
        c2[4 + m] = LD2(f2_2, r2 + m * 128 + cc);
    }
#pragma unroll
    for (int m = 0; m < 7; ++m) {
        c1[9 + m] = LD2(f1_3, r3 + m * 64 + cc);
        c2[9 + m] = LD2(f2_3, r3 + m * 64 + cc);
    }

    // pin: no load may be scheduled after this point, no compute before it
    __builtin_amdgcn_sched_barrier(0);

    // ================ COMPUTE PHASE ================
    // band 0
    ST2(z1 * z2, out, r0 + cc);

    // band 1 (outputs L=0,1)
    {
        f2 A[9], B[9];
#pragma unroll
        for (int M = 0; M < 9; ++M) {
            f2 sa = { 0.f, 0.f }, sb = { 0.f, 0.f };
#pragma unroll
            for (int N = 0; N < 4; ++N)
                if (U9c.u[M * 9 + N] != 0.0f) {
                    sa += U9c.u[M * 9 + N] * a1[N];
                    sb += U9c.u[M * 9 + N] * a2[N];
                }
            A[M] = sa; B[M] = sb;
        }
        f2 C[9];
#pragma unroll
        for (int i = 0; i < 3; ++i)
#pragma unroll
            for (int k = 0; k < 3; ++k) {
                f2 sC = { 0.f, 0.f };
#pragma unroll
                for (int j = 0; j < 3; ++j) sC += A[i * 3 + j] * B[j * 3 + k];
                C[i * 3 + k] = sC;
            }
        f2 y[4];
#pragma unroll
        for (int M = 0; M < 4; ++M) {
            f2 sY = { 0.f, 0.f };
#pragma unroll
            for (int N = 0; N < 9; ++N)
                if (U9c.u[N * 9 + M] != 0.0f) sY += U9c.u[N * 9 + M] * C[N];
            y[M] = sY;
        }
        ST2(y[0], out, r0 + 64 + cc);
#pragma unroll
        for (int m = 0; m < 3; ++m)
            ST2(y[1 + m], out, OUT1_BASE + r1 + m * 192 + cc);
    }

    // band 2 (outputs L=0..2)
    {
        f2 A[9], B[9];
#pragma unroll
        for (int M = 0; M < 9; ++M) {
            f2 sa = { 0.f, 0.f }, sb = { 0.f, 0.f };
#pragma unroll
            for (int N = 0; N < 9; ++N)
                if (U9c.u[M * 9 + N] != 0.0f) {
                    sa += U9c.u[M * 9 + N] * b1[N];
                    sb += U9c.u[M * 9 + N] * b2[N];
                }
            A[M] = sa; B[M] = sb;
        }
        f2 C[9];
#pragma unroll
        for (int i = 0; i < 3; ++i)
#pragma unroll
            for (int k = 0; k < 3; ++k) {
                f2 sC = { 0.f, 0.f };
#pragma unroll
                for (int j = 0; j < 3; ++j) sC += A[i * 3 + j] * B[j * 3 + k];
                C[i * 3 + k] = sC;
            }
        f2 y[9];
#pragma unroll
        for (int M = 0; M < 9; ++M) {
            f2 sY = { 0.f, 0.f };
#pragma unroll
            for (int N = 0; N < 9; ++N)
                if (U9c.u[N * 9 + M] != 0.0f) sY += U9c.u[N * 9 + M] * C[N];
            y[M] = sY;
        }
        ST2(y[0], out, r0 + 128 + cc);
#pragma unroll
        for (int m = 0; m < 3; ++m)
            ST2(y[1 + m], out, OUT1_BASE + r1 + m * 192 + 64 + cc);
#pragma unroll
        for (int m = 0; m < 5; ++m)
            ST2(y[4 + m], out, OUT2_BASE + r2 + m * 128 + cc);
    }

    // band 3 (outputs L=0..3)
    {
        f2 A[25], B[25];
#pragma unroll
        for (int M = 0; M < 25; ++M) {
            f2 sa = { 0.f, 0.f }, sb = { 0.f, 0.f };
#pragma unroll
            for (int N = 0; N < 16; ++N)
                if (U25c.u[M * 25 + N] != 0.0f) {
                    sa += U25c.u[M * 25 + N] * c1[N];
                    sb += U25c.u[M * 25 + N] * c2[N];
                }
            A[M] = sa; B[M] = sb;
        }
        f2 C[25];
#pragma unroll
        for (int i = 0; i < 5; ++i)
#pragma unroll
            for (int k = 0; k < 5; ++k) {
                f2 sC = { 0.f, 0.f };
#pragma unroll
                for (int j = 0; j < 5; ++j) sC += A[i * 5 + j] * B[j * 5 + k];
                C[i * 5 + k] = sC;
            }
        f2 y[16];
#pragma unroll
        for (int M = 0; M < 16; ++M) {
            f2 sY = { 0.f, 0.f };
#pragma unroll
            for (int N = 0; N < 25; ++N)
                if (U25c.u[N * 25 + M] != 0.0f) sY += U25c.u[N * 25 + M] * C[N];
            y[M] = sY;
        }
        ST2(y[0], out, r0 + 192 + cc);
#pragma unroll
        for (int m = 0; m < 3; ++m)
            ST2(y[1 + m], out, OUT1_BASE + r1 + m * 192 + 128 + cc);
#pragma unroll
        for (int m = 0; m < 5; ++m)
            ST2(y[4 + m], out, OUT2_BASE + r2 + m * 128 + 64 + cc);
#pragma unroll
        for (int m = 0; m < 7; ++m)
            ST2(y[9 + m], out, OUT3_BASE + r3 + m * 64 + cc);
    }
#undef LD2
#undef ST2
}

// ---------------- launch ----------------
extern "C" void kernel_launch(void* const* d_in, const int* in_sizes, int n_in,
                              void* d_out, int out_size, void* d_ws, size_t ws_size,
                              hipStream_t stream)
{
    const float* f1_0 = (const float*)d_in[0];
    const float* f1_1 = (const float*)d_in[1];
    const float* f1_2 = (const float*)d_in[2];
    const float* f1_3 = (const float*)d_in[3];
    const float* f2_0 = (const float*)d_in[4];
    const float* f2_1 = (const float*)d_in[5];
    const float* f2_2 = (const float*)d_in[6];
    const float* f2_3 = (const float*)d_in[7];
    float* out = (float*)d_out;

    dim3 blk(256);
    dim3 grid(NS / 8);   // 8 samples per block (2 per wave), 32 channel-pairs

    tp_f2p_kernel<<<grid, blk, 0, stream>>>(f1_0, f1_1, f1_2, f1_3,
                                            f2_0, f2_1, f2_2, f2_3, out);
}